// Round 3
// baseline (242.274 us; speedup 1.0000x reference)
//
#include <hip/hip_runtime.h>

// RangeLoss: out = sum_i[(p-t_adj)^2 + (log p - log t_adj)^2] / N^2
// t_adj = p if (p*1.05 > t && p*0.95 < t) else t.  N = 2^24 -> scale = 2^-48.
//
// R2 findings: 4.8 TB/s mixed L3/HBM read BW, MLP-insensitive. Remaining
// overhead = 2nd launch + 1-block finisher + grid tail. R3: single fused
// kernel, last-block-done final reduce (device-scope atomics, counter in
// d_ws zeroed by hipMemsetAsync each call), 4096 blocks x 16 elems/thread.

constexpr int RL_THREADS = 256;
constexpr int RL_BLOCKS  = 4096;   // 2 generations of 8 blocks/CU
constexpr int RL_UNROLL  = 4;      // float4s per thread (one pass, 16 elems)

__global__ __launch_bounds__(RL_THREADS) void rangeloss_fused(
    const float* __restrict__ preds, const float* __restrict__ target,
    float* __restrict__ out, float* __restrict__ partials,
    unsigned int* __restrict__ counter, int n, float scale) {
  const int tid    = threadIdx.x;
  const int gid    = blockIdx.x * RL_THREADS + tid;
  const int stride = RL_BLOCKS * RL_THREADS;          // in float4 units
  const int n4     = n >> 2;
  const float4* __restrict__ p4 = reinterpret_cast<const float4*>(preds);
  const float4* __restrict__ t4 = reinterpret_cast<const float4*>(target);

  float acc = 0.0f;
  for (int base = gid; base < n4; base += RL_UNROLL * stride) {
    float4 p[RL_UNROLL], t[RL_UNROLL];
    int cnt = 0;
    #pragma unroll
    for (int u = 0; u < RL_UNROLL; ++u)
      if (base + u * stride < n4) { p[u] = p4[base + u * stride]; ++cnt; }
    #pragma unroll
    for (int u = 0; u < RL_UNROLL; ++u)
      if (u < cnt) t[u] = t4[base + u * stride];

    #pragma unroll
    for (int u = 0; u < RL_UNROLL; ++u) {
      if (u < cnt) {
        #pragma unroll
        for (int j = 0; j < 4; ++j) {
          float pj = (&p[u].x)[j];
          float tj = (&t[u].x)[j];
          bool in_range = (pj * 1.05f > tj) && (pj * 0.95f < tj);
          float ta = in_range ? pj : tj;
          float d  = pj - ta;                     // 0 when in_range
          float ld = __logf(pj) - __logf(ta);     // 0 when in_range
          acc += d * d + ld * ld;
        }
      }
    }
  }

  // wave(64) shuffle reduce -> LDS -> block partial
  #pragma unroll
  for (int off = 32; off > 0; off >>= 1) acc += __shfl_down(acc, off, 64);
  __shared__ float smem[RL_THREADS / 64];
  __shared__ int is_last;
  const int lane = tid & 63;
  const int wid  = tid >> 6;
  if (lane == 0) smem[wid] = acc;
  __syncthreads();
  if (tid == 0) {
    float s = 0.0f;
    #pragma unroll
    for (int w = 0; w < RL_THREADS / 64; ++w) s += smem[w];
    // device-visible partial, then arrive
    __hip_atomic_store(&partials[blockIdx.x], s, __ATOMIC_RELEASE,
                       __HIP_MEMORY_SCOPE_AGENT);
    unsigned int old = __hip_atomic_fetch_add(counter, 1u, __ATOMIC_ACQ_REL,
                                              __HIP_MEMORY_SCOPE_AGENT);
    is_last = (old == (unsigned int)(RL_BLOCKS - 1)) ? 1 : 0;
  }
  __syncthreads();

  if (is_last) {
    // last block reduces all partials (fixed order -> deterministic bits)
    float s = 0.0f;
    for (int i = tid; i < RL_BLOCKS; i += RL_THREADS)
      s += __hip_atomic_load(&partials[i], __ATOMIC_ACQUIRE,
                             __HIP_MEMORY_SCOPE_AGENT);
    #pragma unroll
    for (int off = 32; off > 0; off >>= 1) s += __shfl_down(s, off, 64);
    if (lane == 0) smem[wid] = s;
    __syncthreads();
    if (tid == 0) {
      float tot = 0.0f;
      #pragma unroll
      for (int w = 0; w < RL_THREADS / 64; ++w) tot += smem[w];
      out[0] = tot * scale;
    }
  }
}

extern "C" void kernel_launch(void* const* d_in, const int* in_sizes, int n_in,
                              void* d_out, int out_size, void* d_ws, size_t ws_size,
                              hipStream_t stream) {
  const float* preds  = (const float*)d_in[0];
  const float* target = (const float*)d_in[1];
  float* out = (float*)d_out;
  // d_ws layout: [0..3] counter, [256 ..) partials (RL_BLOCKS floats)
  unsigned int* counter = (unsigned int*)d_ws;
  float* partials = (float*)((char*)d_ws + 256);
  const int n = in_sizes[0];

  const float scale = (float)(1.0 / ((double)n * (double)n));

  hipMemsetAsync(counter, 0, sizeof(unsigned int), stream);
  rangeloss_fused<<<RL_BLOCKS, RL_THREADS, 0, stream>>>(
      preds, target, out, partials, counter, n, scale);
}

// Round 4
// 100.979 us; speedup vs baseline: 2.3993x; 2.3993x over previous
//
#include <hip/hip_runtime.h>

// RangeLoss: out = sum_i[(p-t_adj)^2 + (log p - log t_adj)^2] / N^2
// t_adj = p if (p*1.05 > t && p*0.95 < t) else t.  N = 2^24 -> scale = 2^-48.
//
// R3 post-mortem: per-u guarded loads serialized MLP to 1 (VGPR 24, 378us).
// R4: fused single kernel, UNGUARDED batched loads (exact-divisibility fast
// path), threadfence last-block-done finisher. Counter in d_ws, memset each
// call (capture-legal).

constexpr int RL_THREADS = 256;
constexpr int RL_BLOCKS  = 2048;   // 8 blocks/CU, one full resident generation
constexpr int RL_UNROLL  = 4;      // independent float4 pairs in flight

template <bool EXACT>
__global__ __launch_bounds__(RL_THREADS) void rangeloss_fused(
    const float* __restrict__ preds, const float* __restrict__ target,
    float* __restrict__ out, float* __restrict__ partials,
    unsigned int* __restrict__ counter, int n, float scale) {
  const int tid    = threadIdx.x;
  const int gid    = blockIdx.x * RL_THREADS + tid;
  const int stride = RL_BLOCKS * RL_THREADS;          // in float4 units
  const int n4     = n >> 2;
  const float4* __restrict__ p4 = reinterpret_cast<const float4*>(preds);
  const float4* __restrict__ t4 = reinterpret_cast<const float4*>(target);

  float acc = 0.0f;

  if (EXACT) {
    // n4 % (RL_UNROLL*stride) == 0: no guards -> 8 loads batched in flight.
    for (int base = gid; base < n4; base += RL_UNROLL * stride) {
      float4 p[RL_UNROLL], t[RL_UNROLL];
      #pragma unroll
      for (int u = 0; u < RL_UNROLL; ++u) p[u] = p4[base + u * stride];
      #pragma unroll
      for (int u = 0; u < RL_UNROLL; ++u) t[u] = t4[base + u * stride];
      #pragma unroll
      for (int u = 0; u < RL_UNROLL; ++u) {
        #pragma unroll
        for (int j = 0; j < 4; ++j) {
          float pj = (&p[u].x)[j];
          float tj = (&t[u].x)[j];
          bool in_range = (pj * 1.05f > tj) && (pj * 0.95f < tj);
          float ta = in_range ? pj : tj;
          float d  = pj - ta;                     // 0 when in_range
          float ld = __logf(pj) - __logf(ta);     // 0 when in_range
          acc += d * d + ld * ld;
        }
      }
    }
  } else {
    for (int base = gid; base < n4; base += stride) {
      float4 p = p4[base];
      float4 t = t4[base];
      #pragma unroll
      for (int j = 0; j < 4; ++j) {
        float pj = (&p.x)[j];
        float tj = (&t.x)[j];
        bool in_range = (pj * 1.05f > tj) && (pj * 0.95f < tj);
        float ta = in_range ? pj : tj;
        float d  = pj - ta;
        float ld = __logf(pj) - __logf(ta);
        acc += d * d + ld * ld;
      }
    }
  }

  // wave(64) shuffle reduce -> LDS -> block partial
  #pragma unroll
  for (int off = 32; off > 0; off >>= 1) acc += __shfl_down(acc, off, 64);
  __shared__ float smem[RL_THREADS / 64];
  __shared__ int is_last;
  const int lane = tid & 63;
  const int wid  = tid >> 6;
  if (lane == 0) smem[wid] = acc;
  __syncthreads();
  if (tid == 0) {
    float s = 0.0f;
    #pragma unroll
    for (int w = 0; w < RL_THREADS / 64; ++w) s += smem[w];
    partials[blockIdx.x] = s;     // plain store
    __threadfence();              // make it device-visible before arriving
    unsigned int old = atomicAdd(counter, 1u);   // device-scope (m20)
    is_last = (old == (unsigned int)(RL_BLOCKS - 1)) ? 1 : 0;
  }
  __syncthreads();

  if (is_last) {
    __threadfence();  // acquire side: see all blocks' partials
    float s = 0.0f;
    for (int i = tid; i < RL_BLOCKS; i += RL_THREADS)
      s += __hip_atomic_load(&partials[i], __ATOMIC_RELAXED,
                             __HIP_MEMORY_SCOPE_AGENT);
    #pragma unroll
    for (int off = 32; off > 0; off >>= 1) s += __shfl_down(s, off, 64);
    if (lane == 0) smem[wid] = s;
    __syncthreads();
    if (tid == 0) {
      float tot = 0.0f;
      #pragma unroll
      for (int w = 0; w < RL_THREADS / 64; ++w) tot += smem[w];
      out[0] = tot * scale;
    }
  }
}

extern "C" void kernel_launch(void* const* d_in, const int* in_sizes, int n_in,
                              void* d_out, int out_size, void* d_ws, size_t ws_size,
                              hipStream_t stream) {
  const float* preds  = (const float*)d_in[0];
  const float* target = (const float*)d_in[1];
  float* out = (float*)d_out;
  // d_ws layout: [0..255] counter (+pad), [256 ..) partials (RL_BLOCKS floats)
  unsigned int* counter = (unsigned int*)d_ws;
  float* partials = (float*)((char*)d_ws + 256);
  const int n = in_sizes[0];

  const float scale = (float)(1.0 / ((double)n * (double)n));
  const int n4 = n >> 2;
  const int chunk = RL_UNROLL * RL_BLOCKS * RL_THREADS;

  hipMemsetAsync(counter, 0, sizeof(unsigned int), stream);
  if ((n & 3) == 0 && (n4 % chunk) == 0) {
    rangeloss_fused<true><<<RL_BLOCKS, RL_THREADS, 0, stream>>>(
        preds, target, out, partials, counter, n, scale);
  } else {
    rangeloss_fused<false><<<RL_BLOCKS, RL_THREADS, 0, stream>>>(
        preds, target, out, partials, counter, n, scale);
  }
}

// Round 5
// 51.561 us; speedup vs baseline: 4.6988x; 1.9584x over previous
//
#include <hip/hip_runtime.h>

// RangeLoss: out = sum_i[(p-t_adj)^2 + (log p - log t_adj)^2] / N^2
// t_adj = p if (p*1.05 > t && p*0.95 < t) else t.  N = 2^24 -> scale = 2^-48.
//
// R4 post-mortem: __threadfence()/release-store at agent scope emit
// buffer_wbl2/buffer_inv (per-XCD L2 maintenance) -> 2048 L2 flushes destroy
// concurrent load BW (VALUBusy 27%->10%, 3x dur). R5: fence-free sync using
// only atomics (coherent at device scope, no cache ops):
//   atomicExch(partial) -> s_waitcnt vmcnt(0) -> atomicAdd(counter);
//   last block reads partials via atomicAdd(+0.0f) RMW (bit-exact, coherent).

constexpr int RL_THREADS = 256;
constexpr int RL_BLOCKS  = 2048;   // 8 blocks/CU, one resident generation
constexpr int RL_UNROLL  = 4;      // independent float4 pairs in flight

template <bool EXACT>
__global__ __launch_bounds__(RL_THREADS) void rangeloss_fused(
    const float* __restrict__ preds, const float* __restrict__ target,
    float* __restrict__ out, float* __restrict__ partials,
    unsigned int* __restrict__ counter, int n, float scale) {
  const int tid    = threadIdx.x;
  const int gid    = blockIdx.x * RL_THREADS + tid;
  const int stride = RL_BLOCKS * RL_THREADS;          // in float4 units
  const int n4     = n >> 2;
  const float4* __restrict__ p4 = reinterpret_cast<const float4*>(preds);
  const float4* __restrict__ t4 = reinterpret_cast<const float4*>(target);

  float acc = 0.0f;

  if (EXACT) {
    // n4 % (RL_UNROLL*stride) == 0: no guards -> 8 loads batched in flight.
    for (int base = gid; base < n4; base += RL_UNROLL * stride) {
      float4 p[RL_UNROLL], t[RL_UNROLL];
      #pragma unroll
      for (int u = 0; u < RL_UNROLL; ++u) p[u] = p4[base + u * stride];
      #pragma unroll
      for (int u = 0; u < RL_UNROLL; ++u) t[u] = t4[base + u * stride];
      #pragma unroll
      for (int u = 0; u < RL_UNROLL; ++u) {
        #pragma unroll
        for (int j = 0; j < 4; ++j) {
          float pj = (&p[u].x)[j];
          float tj = (&t[u].x)[j];
          bool in_range = (pj * 1.05f > tj) && (pj * 0.95f < tj);
          float ta = in_range ? pj : tj;
          float d  = pj - ta;                     // 0 when in_range
          float ld = __logf(pj) - __logf(ta);     // 0 when in_range
          acc += d * d + ld * ld;
        }
      }
    }
  } else {
    for (int base = gid; base < n4; base += stride) {
      float4 p = p4[base];
      float4 t = t4[base];
      #pragma unroll
      for (int j = 0; j < 4; ++j) {
        float pj = (&p.x)[j];
        float tj = (&t.x)[j];
        bool in_range = (pj * 1.05f > tj) && (pj * 0.95f < tj);
        float ta = in_range ? pj : tj;
        float d  = pj - ta;
        float ld = __logf(pj) - __logf(ta);
        acc += d * d + ld * ld;
      }
    }
  }

  // wave(64) shuffle reduce -> LDS -> block partial
  #pragma unroll
  for (int off = 32; off > 0; off >>= 1) acc += __shfl_down(acc, off, 64);
  __shared__ float smem[RL_THREADS / 64];
  __shared__ int is_last;
  const int lane = tid & 63;
  const int wid  = tid >> 6;
  if (lane == 0) smem[wid] = acc;
  __syncthreads();
  if (tid == 0) {
    float s = 0.0f;
    #pragma unroll
    for (int w = 0; w < RL_THREADS / 64; ++w) s += smem[w];
    // Publish partial with an ATOMIC (coherent at device scope, no cache
    // maintenance), drain vmcnt so it is globally visible, then arrive.
    atomicExch(&partials[blockIdx.x], s);
    asm volatile("s_waitcnt vmcnt(0)" ::: "memory");
    unsigned int old = atomicAdd(counter, 1u);   // device-scope (m20)
    is_last = (old == (unsigned int)(RL_BLOCKS - 1)) ? 1 : 0;
  }
  __syncthreads();

  if (is_last) {
    // Coherent read of every partial via atomic RMW (+0.0f is bit-exact for
    // the non-negative partials). Fixed order -> deterministic result.
    float s = 0.0f;
    for (int i = tid; i < RL_BLOCKS; i += RL_THREADS)
      s += atomicAdd(&partials[i], 0.0f);
    #pragma unroll
    for (int off = 32; off > 0; off >>= 1) s += __shfl_down(s, off, 64);
    if (lane == 0) smem[wid] = s;
    __syncthreads();
    if (tid == 0) {
      float tot = 0.0f;
      #pragma unroll
      for (int w = 0; w < RL_THREADS / 64; ++w) tot += smem[w];
      out[0] = tot * scale;
    }
  }
}

extern "C" void kernel_launch(void* const* d_in, const int* in_sizes, int n_in,
                              void* d_out, int out_size, void* d_ws, size_t ws_size,
                              hipStream_t stream) {
  const float* preds  = (const float*)d_in[0];
  const float* target = (const float*)d_in[1];
  float* out = (float*)d_out;
  // d_ws layout: [0..255] counter (+pad), [256 ..) partials (RL_BLOCKS floats)
  unsigned int* counter = (unsigned int*)d_ws;
  float* partials = (float*)((char*)d_ws + 256);
  const int n = in_sizes[0];

  const float scale = (float)(1.0 / ((double)n * (double)n));
  const int n4 = n >> 2;
  const int chunk = RL_UNROLL * RL_BLOCKS * RL_THREADS;

  hipMemsetAsync(counter, 0, sizeof(unsigned int), stream);
  if ((n & 3) == 0 && (n4 % chunk) == 0) {
    rangeloss_fused<true><<<RL_BLOCKS, RL_THREADS, 0, stream>>>(
        preds, target, out, partials, counter, n, scale);
  } else {
    rangeloss_fused<false><<<RL_BLOCKS, RL_THREADS, 0, stream>>>(
        preds, target, out, partials, counter, n, scale);
  }
}

// Round 8
// 34.405 us; speedup vs baseline: 7.0418x; 1.4987x over previous
//
#include <hip/hip_runtime.h>

// RangeLoss: out = sum_i[(p-t_adj)^2 + (log p - log t_adj)^2] / N^2
// t_adj = p if (p*1.05 > t && p*0.95 < t) else t.  N = 2^24 -> scale = 2^-48.
//
// R7 compile fix: __builtin_nontemporal_load needs a native vector type, not
// HIP_vector_type. Use ext_vector_type(4) float for the preds (nontemporal)
// path. Theory unchanged: preds streams HBM without L3 allocation; target
// (64MB) owns the L3 -> overlap HBM and L3 paths instead of 50/50 thrash at
// 4.87 TB/s.

typedef float f32x4 __attribute__((ext_vector_type(4)));

constexpr int RL_THREADS = 256;
constexpr int RL_BLOCKS  = 2048;   // 8 blocks/CU, one resident generation
constexpr int RL_UNROLL  = 4;      // independent float4 pairs in flight

__global__ __launch_bounds__(RL_THREADS) void rangeloss_partial(
    const float* __restrict__ preds, const float* __restrict__ target,
    float* __restrict__ partials, int n) {
  const int tid    = blockIdx.x * RL_THREADS + threadIdx.x;
  const int stride = RL_BLOCKS * RL_THREADS;          // in float4 units
  const int n4     = n >> 2;
  const f32x4* __restrict__ p4 = reinterpret_cast<const f32x4*>(preds);
  const f32x4* __restrict__ t4 = reinterpret_cast<const f32x4*>(target);

  float acc = 0.0f;

  int base = tid;
  for (; base + (RL_UNROLL - 1) * stride < n4; base += RL_UNROLL * stride) {
    f32x4 p[RL_UNROLL], t[RL_UNROLL];
    #pragma unroll
    for (int u = 0; u < RL_UNROLL; ++u)
      p[u] = __builtin_nontemporal_load(&p4[base + u * stride]);  // no L3 alloc
    #pragma unroll
    for (int u = 0; u < RL_UNROLL; ++u)
      t[u] = t4[base + u * stride];                               // L3-cached

    #pragma unroll
    for (int u = 0; u < RL_UNROLL; ++u) {
      #pragma unroll
      for (int j = 0; j < 4; ++j) {
        float pj = p[u][j];
        float tj = t[u][j];
        bool in_range = (pj * 1.05f > tj) && (pj * 0.95f < tj);
        float ta = in_range ? pj : tj;
        float d  = pj - ta;                     // 0 when in_range
        float ld = __logf(pj) - __logf(ta);     // 0 when in_range
        acc += d * d + ld * ld;
      }
    }
  }
  // Tail (unused for N=2^24; kept for generality).
  for (; base < n4; base += stride) {
    f32x4 p = p4[base];
    f32x4 t = t4[base];
    #pragma unroll
    for (int j = 0; j < 4; ++j) {
      float pj = p[j];
      float tj = t[j];
      bool in_range = (pj * 1.05f > tj) && (pj * 0.95f < tj);
      float ta = in_range ? pj : tj;
      float d  = pj - ta;
      float ld = __logf(pj) - __logf(ta);
      acc += d * d + ld * ld;
    }
  }

  // wave(64) shuffle reduce
  #pragma unroll
  for (int off = 32; off > 0; off >>= 1) acc += __shfl_down(acc, off, 64);

  __shared__ float smem[RL_THREADS / 64];
  const int lane = threadIdx.x & 63;
  const int wid  = threadIdx.x >> 6;
  if (lane == 0) smem[wid] = acc;
  __syncthreads();
  if (threadIdx.x == 0) {
    float s = 0.0f;
    #pragma unroll
    for (int w = 0; w < RL_THREADS / 64; ++w) s += smem[w];
    partials[blockIdx.x] = s;
  }
}

__global__ __launch_bounds__(RL_THREADS) void rangeloss_final(
    const float* __restrict__ partials, float* __restrict__ out, float scale) {
  float acc = 0.0f;
  for (int i = threadIdx.x; i < RL_BLOCKS; i += RL_THREADS) acc += partials[i];
  #pragma unroll
  for (int off = 32; off > 0; off >>= 1) acc += __shfl_down(acc, off, 64);

  __shared__ float smem[RL_THREADS / 64];
  const int lane = threadIdx.x & 63;
  const int wid  = threadIdx.x >> 6;
  if (lane == 0) smem[wid] = acc;
  __syncthreads();
  if (threadIdx.x == 0) {
    float s = 0.0f;
    #pragma unroll
    for (int w = 0; w < RL_THREADS / 64; ++w) s += smem[w];
    out[0] = s * scale;
  }
}

extern "C" void kernel_launch(void* const* d_in, const int* in_sizes, int n_in,
                              void* d_out, int out_size, void* d_ws, size_t ws_size,
                              hipStream_t stream) {
  const float* preds  = (const float*)d_in[0];
  const float* target = (const float*)d_in[1];
  float* out      = (float*)d_out;
  float* partials = (float*)d_ws;          // RL_BLOCKS floats = 8 KiB
  const int n = in_sizes[0];

  // loss = sum / (n * n); n = 2^24 -> exact 2^-48
  const float scale = (float)(1.0 / ((double)n * (double)n));

  rangeloss_partial<<<RL_BLOCKS, RL_THREADS, 0, stream>>>(preds, target, partials, n);
  rangeloss_final<<<1, RL_THREADS, 0, stream>>>(partials, out, scale);
}

// Round 9
// 33.750 us; speedup vs baseline: 7.1784x; 1.0194x over previous
//
#include <hip/hip_runtime.h>

// RangeLoss: out = sum_i[(p-t_adj)^2 + (log p - log t_adj)^2] / N^2
// t_adj = p if (p*1.05 > t && p*0.95 < t) else t.  N = 2^24 -> scale = 2^-48.
//
// R8 post-mortem: nontemporal = null (FETCH unchanged 65.5MB, -8% perf).
// Main loop pinned at ~4.87 TB/s demand across 3 variants == m146's measured
// reduction ceiling (4.89). Concede the loop; recover the ~4.3us two-kernel
// overhead via fence-free fused finale:
//   - block 0 snapshots counter at entry (safe: arrivals trail by >=20us main
//     loop; all blocks co-resident, occupancy-gated host-side)
//   - publish: atomicExch(partial) -> s_waitcnt vmcnt(0) -> atomicAdd(counter)
//   - block 0 spins until counter-c_start >= gridDim.x (wrap-safe, ANY start
//     value incl. 0xAA poison -- fixes R6), then fixed-order reduce.
// No __threadfence (R4: emits L2 writeback/inv, 3x slowdown). No memset node.

typedef float f32x4 __attribute__((ext_vector_type(4)));

constexpr int RL_THREADS   = 256;
constexpr int RL_MAXBLOCKS = 2048;   // 256 CU x 8 blocks/CU
constexpr int RL_UNROLL    = 4;

template <bool EXACT>
__global__ __launch_bounds__(RL_THREADS) void rangeloss_fused(
    const float* __restrict__ preds, const float* __restrict__ target,
    float* __restrict__ out, float* __restrict__ partials,
    unsigned int* __restrict__ counter, int n, float scale) {
  const int tid = threadIdx.x;

  // Snapshot arrival-counter base (block 0, thread 0 only; used post-spin by
  // the same thread -- no sync needed). Safe: no block can arrive until its
  // >=20us main loop completes; dispatch ramp is ~us.
  unsigned int c_start = 0;
  if (blockIdx.x == 0 && tid == 0)
    c_start = __hip_atomic_load(counter, __ATOMIC_RELAXED,
                                __HIP_MEMORY_SCOPE_AGENT);

  const int gid    = blockIdx.x * RL_THREADS + tid;
  const int stride = gridDim.x * RL_THREADS;          // in float4 units
  const int n4     = n >> 2;
  const f32x4* __restrict__ p4 = reinterpret_cast<const f32x4*>(preds);
  const f32x4* __restrict__ t4 = reinterpret_cast<const f32x4*>(target);

  float acc = 0.0f;

  if (EXACT) {
    // n4 % (RL_UNROLL*stride) == 0: unguarded -> 8 loads batched in flight.
    for (int base = gid; base < n4; base += RL_UNROLL * stride) {
      f32x4 p[RL_UNROLL], t[RL_UNROLL];
      #pragma unroll
      for (int u = 0; u < RL_UNROLL; ++u) p[u] = p4[base + u * stride];
      #pragma unroll
      for (int u = 0; u < RL_UNROLL; ++u) t[u] = t4[base + u * stride];
      #pragma unroll
      for (int u = 0; u < RL_UNROLL; ++u) {
        #pragma unroll
        for (int j = 0; j < 4; ++j) {
          float pj = p[u][j];
          float tj = t[u][j];
          bool in_range = (pj * 1.05f > tj) && (pj * 0.95f < tj);
          float ta = in_range ? pj : tj;
          float d  = pj - ta;                     // 0 when in_range
          float ld = __logf(pj) - __logf(ta);     // 0 when in_range
          acc += d * d + ld * ld;
        }
      }
    }
  } else {
    for (int base = gid; base < n4; base += stride) {
      f32x4 p = p4[base];
      f32x4 t = t4[base];
      #pragma unroll
      for (int j = 0; j < 4; ++j) {
        float pj = p[j];
        float tj = t[j];
        bool in_range = (pj * 1.05f > tj) && (pj * 0.95f < tj);
        float ta = in_range ? pj : tj;
        float d  = pj - ta;
        float ld = __logf(pj) - __logf(ta);
        acc += d * d + ld * ld;
      }
    }
  }

  // wave(64) shuffle reduce -> LDS -> block partial
  #pragma unroll
  for (int off = 32; off > 0; off >>= 1) acc += __shfl_down(acc, off, 64);
  __shared__ float smem[RL_THREADS / 64];
  const int lane = tid & 63;
  const int wid  = tid >> 6;
  if (lane == 0) smem[wid] = acc;
  __syncthreads();
  if (tid == 0) {
    float s = 0.0f;
    #pragma unroll
    for (int w = 0; w < RL_THREADS / 64; ++w) s += smem[w];
    // Publish (coherent atomic, no cache maintenance), drain, arrive.
    atomicExch(&partials[blockIdx.x], s);
    asm volatile("s_waitcnt vmcnt(0)" ::: "memory");
    atomicAdd(counter, 1u);                       // device-scope (m20)
    if (blockIdx.x == 0) {
      // Spin until all gridDim.x arrivals of THIS dispatch (unsigned diff:
      // correct for any c_start, robust to wraparound / 0xAA poison).
      while ((unsigned int)(__hip_atomic_load(counter, __ATOMIC_RELAXED,
                                              __HIP_MEMORY_SCOPE_AGENT)
                            - c_start) < gridDim.x)
        __builtin_amdgcn_s_sleep(2);
    }
  }

  if (blockIdx.x == 0) {
    __syncthreads();   // other threads of block 0 wait for tid0's spin
    float s = 0.0f;
    for (int i = tid; i < (int)gridDim.x; i += RL_THREADS)
      s += __hip_atomic_load(&partials[i], __ATOMIC_RELAXED,
                             __HIP_MEMORY_SCOPE_AGENT);
    #pragma unroll
    for (int off = 32; off > 0; off >>= 1) s += __shfl_down(s, off, 64);
    __syncthreads();   // smem reuse guard
    if (lane == 0) smem[wid] = s;
    __syncthreads();
    if (tid == 0) {
      float tot = 0.0f;
      #pragma unroll
      for (int w = 0; w < RL_THREADS / 64; ++w) tot += smem[w];
      out[0] = tot * scale;
    }
  }
}

// Fallback two-kernel path (used only if co-residency can't be guaranteed).
__global__ __launch_bounds__(RL_THREADS) void rangeloss_partial(
    const float* __restrict__ preds, const float* __restrict__ target,
    float* __restrict__ partials, int n, int nblocks) {
  const int tid    = blockIdx.x * RL_THREADS + threadIdx.x;
  const int stride = nblocks * RL_THREADS;
  const int n4     = n >> 2;
  const f32x4* __restrict__ p4 = reinterpret_cast<const f32x4*>(preds);
  const f32x4* __restrict__ t4 = reinterpret_cast<const f32x4*>(target);
  float acc = 0.0f;
  for (int base = tid; base < n4; base += stride) {
    f32x4 p = p4[base];
    f32x4 t = t4[base];
    #pragma unroll
    for (int j = 0; j < 4; ++j) {
      float pj = p[j];
      float tj = t[j];
      bool in_range = (pj * 1.05f > tj) && (pj * 0.95f < tj);
      float ta = in_range ? pj : tj;
      float d  = pj - ta;
      float ld = __logf(pj) - __logf(ta);
      acc += d * d + ld * ld;
    }
  }
  #pragma unroll
  for (int off = 32; off > 0; off >>= 1) acc += __shfl_down(acc, off, 64);
  __shared__ float smem[RL_THREADS / 64];
  if ((threadIdx.x & 63) == 0) smem[threadIdx.x >> 6] = acc;
  __syncthreads();
  if (threadIdx.x == 0) {
    float s = 0.0f;
    #pragma unroll
    for (int w = 0; w < RL_THREADS / 64; ++w) s += smem[w];
    partials[blockIdx.x] = s;
  }
}

__global__ __launch_bounds__(RL_THREADS) void rangeloss_final(
    const float* __restrict__ partials, float* __restrict__ out, float scale,
    int nblocks) {
  float acc = 0.0f;
  for (int i = threadIdx.x; i < nblocks; i += RL_THREADS) acc += partials[i];
  #pragma unroll
  for (int off = 32; off > 0; off >>= 1) acc += __shfl_down(acc, off, 64);
  __shared__ float smem[RL_THREADS / 64];
  if ((threadIdx.x & 63) == 0) smem[threadIdx.x >> 6] = acc;
  __syncthreads();
  if (threadIdx.x == 0) {
    float s = 0.0f;
    #pragma unroll
    for (int w = 0; w < RL_THREADS / 64; ++w) s += smem[w];
    out[0] = s * scale;
  }
}

extern "C" void kernel_launch(void* const* d_in, const int* in_sizes, int n_in,
                              void* d_out, int out_size, void* d_ws, size_t ws_size,
                              hipStream_t stream) {
  const float* preds  = (const float*)d_in[0];
  const float* target = (const float*)d_in[1];
  float* out = (float*)d_out;
  // d_ws layout: [0..255] counter (+pad), [256 ..) partials
  unsigned int* counter = (unsigned int*)d_ws;
  float* partials = (float*)((char*)d_ws + 256);
  const int n = in_sizes[0];

  const float scale = (float)(1.0 / ((double)n * (double)n));
  const int n4 = n >> 2;

  // Co-residency gate: fused spin-sync requires all blocks resident.
  int max_per_cu = 0;
  hipError_t qe = hipOccupancyMaxActiveBlocksPerMultiprocessor(
      &max_per_cu, rangeloss_fused<true>, RL_THREADS, 0);
  if (qe == hipSuccess && max_per_cu >= 1) {
    int grid = max_per_cu * 256;                 // 256 CUs on MI355X
    if (grid > RL_MAXBLOCKS) grid = RL_MAXBLOCKS;
    const long chunk = (long)RL_UNROLL * grid * RL_THREADS;
    if ((n & 3) == 0 && ((long)n4 % chunk) == 0) {
      rangeloss_fused<true><<<grid, RL_THREADS, 0, stream>>>(
          preds, target, out, partials, counter, n, scale);
    } else {
      rangeloss_fused<false><<<grid, RL_THREADS, 0, stream>>>(
          preds, target, out, partials, counter, n, scale);
    }
  } else {
    rangeloss_partial<<<RL_MAXBLOCKS, RL_THREADS, 0, stream>>>(
        preds, target, partials, n, RL_MAXBLOCKS);
    rangeloss_final<<<1, RL_THREADS, 0, stream>>>(
        partials, out, scale, RL_MAXBLOCKS);
  }
}